// Round 2
// baseline (696.933 us; speedup 1.0000x reference)
//
#include <hip/hip_runtime.h>

// RoIAlign-style bilinear ROI resize.
// feature_map: (B=8, C=256, H=200, W=200) f32
// proposals:   (B=8, N=256, 4) int32  [x1,y1,x2,y2]
// output:      (R=2048, C=256, 7, 7) f32
//
// Mapping: one block per ROI (2048 blocks, 256 threads = 4 waves).
// lane (0..48) = output bin (sy,sx); wave = channel phase; loop c += 4.
// All tap offsets/weights are channel-invariant -> computed once per thread.
//
// XCD-affinity swizzle: hardware dispatches blocks round-robin over 8 XCDs
// (bid % 8 = XCD). We remap r = (bid%8)*256 + bid/8 so XCD i processes
// exactly image i's 256 ROIs -> each XCD streams ONE 40 MB image through its
// private 4 MiB L2; the per-channel union of box lines (~1.8 MB) is L2-
// resident. 2048 % 8 == 0 so the remap is bijective.

#define C_DIM 256
#define H_DIM 200
#define W_DIM 200
#define S_DIM 7
#define N_ROI 256   // ROIs per image
#define NXCD  8

__global__ __launch_bounds__(256) void roialign_kernel(
    const float* __restrict__ fm,
    const int*   __restrict__ props,
    float*       __restrict__ out,
    int R)
{
    // XCD-affinity remap: image index = bid % 8 (the XCD this block lands on)
    const int bid = blockIdx.x;
    const int r = (bid & (NXCD - 1)) * (R / NXCD) + (bid >> 3);
    const int b = r >> 8;  // image index (N_ROI = 256 ROIs per image)

    // Box (clamped)
    int bx1 = props[r * 4 + 0];
    int by1 = props[r * 4 + 1];
    int bx2 = props[r * 4 + 2];
    int by2 = props[r * 4 + 3];
    bx1 = min(max(bx1, 0), W_DIM - 1);
    by1 = min(max(by1, 0), H_DIM - 1);
    bx2 = min(max(bx2, 0), W_DIM - 1);
    by2 = min(max(by2, 0), H_DIM - 1);
    const int h = by2 - by1 + 1;
    const int w = bx2 - bx1 + 1;

    const int l  = threadIdx.x & 63;   // lane: bin index (49 active)
    const int wv = threadIdx.x >> 6;   // wave: channel phase 0..3
    const bool active = (l < S_DIM * S_DIM);

    const int sy = l / 7;
    const int sx = l - sy * 7;

    // Bilinear source coords (matches reference exactly, fp32 math)
    float src_y = fmaxf(((float)sy + 0.5f) * (float)h * (1.0f / S_DIM) - 0.5f, 0.0f);
    float src_x = fmaxf(((float)sx + 0.5f) * (float)w * (1.0f / S_DIM) - 0.5f, 0.0f);
    const float y0f = floorf(src_y);
    const float x0f = floorf(src_x);
    const float wy = src_y - y0f;
    const float wx = src_x - x0f;
    const int y0 = (int)y0f;
    const int x0 = (int)x0f;
    const int y1 = min(y0 + 1, h - 1);
    const int x1 = min(x0 + 1, w - 1);
    const int ya0 = by1 + y0, ya1 = by1 + y1;
    const int xa0 = bx1 + x0, xa1 = bx1 + x1;

    const int o00 = ya0 * W_DIM + xa0;
    const int o01 = ya0 * W_DIM + xa1;
    const int o10 = ya1 * W_DIM + xa0;
    const int o11 = ya1 * W_DIM + xa1;
    const float w00 = (1.0f - wy) * (1.0f - wx);
    const float w01 = (1.0f - wy) * wx;
    const float w10 = wy * (1.0f - wx);
    const float w11 = wy * wx;

    const float* base = fm + ((size_t)b * C_DIM + wv) * (size_t)(H_DIM * W_DIM);
    float*       ob   = out + ((size_t)r * C_DIM + wv) * (S_DIM * S_DIM) + l;

    #pragma unroll 4
    for (int c = wv; c < C_DIM; c += 4) {
        if (active) {
            const float v00 = base[o00];
            const float v01 = base[o01];
            const float v10 = base[o10];
            const float v11 = base[o11];
            *ob = v00 * w00 + v01 * w01 + v10 * w10 + v11 * w11;
        }
        base += 4 * (size_t)(H_DIM * W_DIM);
        ob   += 4 * (S_DIM * S_DIM);
    }
}

extern "C" void kernel_launch(void* const* d_in, const int* in_sizes, int n_in,
                              void* d_out, int out_size, void* d_ws, size_t ws_size,
                              hipStream_t stream)
{
    const float* fm    = (const float*)d_in[0];
    const int*   props = (const int*)d_in[1];
    float*       out   = (float*)d_out;

    const int R = in_sizes[1] / 4;  // 2048
    roialign_kernel<<<R, 256, 0, stream>>>(fm, props, out, R);
}

// Round 3
// 557.550 us; speedup vs baseline: 1.2500x; 1.2500x over previous
//
#include <hip/hip_runtime.h>

// RoIAlign via LDS-staged channel planes.
// feature_map: (B=8, C=256, H=200, W=200) f32
// proposals:   (B=8, N=256, 4) int32
// output:      (R=2048, C=256, 7, 7) f32
//
// Round-2 post-mortem: ROI-per-block gather fetched 916 MB from HBM (2.8x
// over-fetch, 2.5 TB/s effective, 371 us) because per-XCD L2 (4 MiB) cannot
// hold the ~40 MB of planes its 256 concurrent ROI-blocks gather from.
//
// This version inverts the loop: one block per (image, channel, row-half).
// The block stages its row-slab with perfectly coalesced float4 loads
// (feature map read from HBM EXACTLY once), then all 256 ROIs gather their
// bilinear taps from LDS. Halves: rows 0..100 (101 rows) / rows 100..199
// (100 rows); a tap pair (ya0, ya0+1) always fits one half. 80.8 KB LDS
// -> 2 blocks/CU, so block A's compute overlaps block B's staging.

#define B_DIM 8
#define C_DIM 256
#define H_DIM 200
#define W_DIM 200
#define S_DIM 7
#define NBINS (S_DIM * S_DIM)   // 49
#define NROI  256               // ROIs per image
#define THREADS 512
#define ROWS_HALF0 101          // rows 0..100
#define ROWS_HALF1 100          // rows 100..199
#define LDS_BYTES (ROWS_HALF0 * W_DIM * 4)   // 80,800 B -> 2 blocks/CU

__global__ __launch_bounds__(THREADS) void roialign_kernel(
    const float* __restrict__ fm,
    const int*   __restrict__ props,
    float*       __restrict__ out)
{
    extern __shared__ float sPlane[];

    const int bid  = blockIdx.x;
    const int half = bid & 1;
    const int c    = (bid >> 1) & (C_DIM - 1);
    const int b    = bid >> 9;

    const int r0      = half ? 100 : 0;
    const int nchunks = (half ? ROWS_HALF1 : ROWS_HALF0) * (W_DIM / 4);  // float4 chunks

    const int tid = threadIdx.x;

    // ---- stage rows [r0, r0+nrows) of plane (b,c): coalesced float4 stream ----
    const float4* __restrict__ src =
        (const float4*)(fm + ((size_t)(b * C_DIM + c)) * (H_DIM * W_DIM) + (size_t)r0 * W_DIM);
    float4* dst = (float4*)sPlane;
    for (int k = tid; k < nchunks; k += THREADS)
        dst[k] = src[k];
    __syncthreads();

    // ---- gather: item = roi*49 + bin ----
    const int4* __restrict__ pbase = (const int4*)props + (size_t)b * NROI;

    for (int item = tid; item < NROI * NBINS; item += THREADS) {
        const int roi = item / NBINS;
        const int bin = item - roi * NBINS;
        const int sy  = bin / S_DIM;
        const int sx  = bin - sy * S_DIM;

        const int4 p = pbase[roi];
        const int bx1 = min(max(p.x, 0), W_DIM - 1);
        const int by1 = min(max(p.y, 0), H_DIM - 1);
        const int bx2 = min(max(p.z, 0), W_DIM - 1);
        const int by2 = min(max(p.w, 0), H_DIM - 1);
        const int h = by2 - by1 + 1;
        const int w = bx2 - bx1 + 1;

        // y path first: ownership test before doing x work (math identical to round-2 kernel)
        const float src_y = fmaxf(((float)sy + 0.5f) * (float)h * (1.0f / S_DIM) - 0.5f, 0.0f);
        const float y0f = floorf(src_y);
        const float wy  = src_y - y0f;
        const int y0  = (int)y0f;
        const int y1  = min(y0 + 1, h - 1);
        const int ya0 = by1 + y0;
        const int ya1 = by1 + y1;

        // half 0 owns ya0 <= 99 (then ya1 <= 100); half 1 owns ya0 >= 100 (ya1 <= 199)
        const bool mine = half ? (ya0 >= 100) : (ya0 <= 99);
        if (!mine) continue;

        const float src_x = fmaxf(((float)sx + 0.5f) * (float)w * (1.0f / S_DIM) - 0.5f, 0.0f);
        const float x0f = floorf(src_x);
        const float wx  = src_x - x0f;
        const int x0  = (int)x0f;
        const int x1  = min(x0 + 1, w - 1);
        const int xa0 = bx1 + x0;
        const int xa1 = bx1 + x1;

        const int ry0 = ya0 - r0;
        const int ry1 = ya1 - r0;
        const float v00 = sPlane[ry0 * W_DIM + xa0];
        const float v01 = sPlane[ry0 * W_DIM + xa1];
        const float v10 = sPlane[ry1 * W_DIM + xa0];
        const float v11 = sPlane[ry1 * W_DIM + xa1];

        const float w00 = (1.0f - wy) * (1.0f - wx);
        const float w01 = (1.0f - wy) * wx;
        const float w10 = wy * (1.0f - wx);
        const float w11 = wy * wx;

        const int r = b * NROI + roi;
        out[((size_t)r * C_DIM + c) * NBINS + bin] =
            v00 * w00 + v01 * w01 + v10 * w10 + v11 * w11;
    }
}

extern "C" void kernel_launch(void* const* d_in, const int* in_sizes, int n_in,
                              void* d_out, int out_size, void* d_ws, size_t ws_size,
                              hipStream_t stream)
{
    const float* fm    = (const float*)d_in[0];
    const int*   props = (const int*)d_in[1];
    float*       out   = (float*)d_out;

    // 80.8 KB dynamic LDS (> default 64 KB cap) — opt in every call (idempotent,
    // host-side, graph-capture safe).
    hipFuncSetAttribute((const void*)roialign_kernel,
                        hipFuncAttributeMaxDynamicSharedMemorySize, LDS_BYTES);

    const int grid = B_DIM * C_DIM * 2;  // 4096 blocks: (b, c, half)
    roialign_kernel<<<grid, THREADS, LDS_BYTES, stream>>>(fm, props, out);
}